// Round 19
// baseline (327.408 us; speedup 1.0000x reference)
//
#include <hip/hip_runtime.h>
#include <math.h>

#define NN 50000
#define EE 800000
#define BM 64
#define HB 3125                  // hist blocks (EE/256 exactly)
#define DB 5000                  // dot blocks
#define DS3 (DB * 256)           // 1,280,000; (EE*16) % (DS3*2) == 0 -> 5 iters
#define TB2 391                  // transform blocks (each does 2 tiles; 782 tiles total)

typedef float f4 __attribute__((ext_vector_type(4)));
typedef int   i2 __attribute__((ext_vector_type(2)));

// ---------------- helpers ----------------

#define FMA4(acc, s, v) do { \
    (acc).x = fmaf((s), (v).x, (acc).x); \
    (acc).y = fmaf((s), (v).y, (acc).y); \
    (acc).z = fmaf((s), (v).z, (acc).z); \
    (acc).w = fmaf((s), (v).w, (acc).w); } while (0)

__device__ __forceinline__ float dot4(float4 u, float4 v) {
    return fmaf(u.x, v.x, fmaf(u.y, v.y, fmaf(u.z, v.z, u.w * v.w)));
}

// pack two finite floats to bf16 (RNE) in one uint: lo = feature even, hi = odd
__device__ __forceinline__ unsigned pk_bf16(float lo, float hi) {
    union { float f; unsigned u; } a, b;
    a.f = lo; b.f = hi;
    unsigned alo = (a.u + 0x7FFFu + ((a.u >> 16) & 1u)) >> 16;
    unsigned bhi = (b.u + 0x7FFFu + ((b.u >> 16) & 1u)) >> 16;
    return (bhi << 16) | alo;
}

// ---------------- fused edge dots + histogram (dot blocks FIRST) ----------------

__global__ __launch_bounds__(256) void hist_dot(
    const int* __restrict__ dst, int* __restrict__ deg, int* __restrict__ rank,
    const float* __restrict__ et0, const float* __restrict__ et1,
    const float* __restrict__ a0, const float* __restrict__ a1,
    float* __restrict__ sc0, float* __restrict__ sc1)
{
    const int bid = blockIdx.x;

    if (bid < DB) {
        // streaming edge dots (NT loads, lane-contiguous, 2-deep unroll)
        const int tid  = bid * 256 + threadIdx.x;
        const int lane = threadIdx.x & 63;
        const int p    = tid & 15;
        const float4 A0 = *reinterpret_cast<const float4*>(a0 + 128 + p * 4);
        const float4 A1 = *reinterpret_cast<const float4*>(a1 + 128 + p * 4);
        const f4* __restrict__ e0 = reinterpret_cast<const f4*>(et0);
        const f4* __restrict__ e1 = reinterpret_cast<const f4*>(et1);

        for (int i = tid; i < EE * 16; i += DS3 * 2) {
            f4 v0[2], v1[2];
#pragma unroll
            for (int u = 0; u < 2; u++) v0[u] = __builtin_nontemporal_load(e0 + i + u * DS3);
#pragma unroll
            for (int u = 0; u < 2; u++) v1[u] = __builtin_nontemporal_load(e1 + i + u * DS3);
            float r0[2], r1[2];
#pragma unroll
            for (int u = 0; u < 2; u++) {
                r0[u] = fmaf(v0[u][0], A0.x, fmaf(v0[u][1], A0.y, fmaf(v0[u][2], A0.z, v0[u][3] * A0.w)));
                r1[u] = fmaf(v1[u][0], A1.x, fmaf(v1[u][1], A1.y, fmaf(v1[u][2], A1.z, v1[u][3] * A1.w)));
            }
#pragma unroll
            for (int u = 0; u < 2; u++) {
#pragma unroll
                for (int off = 8; off; off >>= 1) {
                    r0[u] += __shfl_xor(r0[u], off);
                    r1[u] += __shfl_xor(r1[u], off);
                }
            }
            if ((lane & 15) == 0) {
#pragma unroll
                for (int u = 0; u < 2; u++) {
                    const int e = (i + u * DS3) >> 4;
                    sc0[e] = r0[u];
                    sc1[e] = r1[u];
                }
            }
        }
    } else {
        // histogram + per-edge rank (atomicAdd return = rank within segment)
        const int e = (bid - DB) * 256 + threadIdx.x;   // HB*256 == EE exactly
        rank[e] = atomicAdd(&deg[dst[e]], 1);
    }
}

// ---------------- atomic-free scatter: epX[p] = {src, score bits}, nt stores ----------------

__global__ __launch_bounds__(256) void k_scatter(
    const int* __restrict__ src, const int* __restrict__ dst,
    const int* __restrict__ rowptr, const int* __restrict__ rank,
    const float* __restrict__ sc0, const float* __restrict__ sc1,
    i2* __restrict__ epA, i2* __restrict__ epB)
{
    int e = blockIdx.x * 256 + threadIdx.x;
    if (e < EE) {
        const int p = rowptr[dst[e]] + rank[e];
        const int s = src[e];
        i2 ra; ra[0] = s; ra[1] = __float_as_int(sc0[e]);
        i2 rb; rb[0] = s; rb[1] = __float_as_int(sc1[e]);
        __builtin_nontemporal_store(ra, epA + p);
        __builtin_nontemporal_store(rb, epB + p);
    }
}

// ---------------- node transform (LDS-tiled GEMM, 2 tiles/block) + fused scan ----------------

__global__ __launch_bounds__(256) void node_transform(
    const float* __restrict__ hin, const float* __restrict__ pot,
    const float* __restrict__ Wpot, const float* __restrict__ bpot,
    const float* __restrict__ fcW, const float* __restrict__ fcU,
    const float* __restrict__ a, const float* __restrict__ gate,
    unsigned* __restrict__ zb, float* __restrict__ zs, float* __restrict__ zd,
    unsigned* __restrict__ bb,
    const int* __restrict__ deg, int* __restrict__ rowptr, int do_scan)
{
    __shared__ float sAt[64][64];
    __shared__ float sB[64][128];
    __shared__ float sPot[64][16];
    __shared__ float sWp[16][64];

    const int t = threadIdx.x;

    if (do_scan && blockIdx.x == TB2) {
        // 256-thread exclusive scan of deg -> rowptr (rides in this dispatch)
        int* part = reinterpret_cast<int*>(&sAt[0][0]);
        const int CH = (NN + 255) / 256;
        const int b  = t * CH;
        const int e  = min(b + CH, NN);
        int sum = 0;
        for (int i = b; i < e; i++) sum += deg[i];
        part[t] = sum;
        __syncthreads();
        for (int off = 1; off < 256; off <<= 1) {
            int v = (t >= off) ? part[t - off] : 0;
            __syncthreads();
            part[t] += v;
            __syncthreads();
        }
        int run = (t == 0) ? 0 : part[t - 1];
        for (int i = b; i < e; i++) {
            rowptr[i] = run;
            run += deg[i];
        }
        if (t == 0) rowptr[NN] = EE;
        return;
    }

    // stage weights ONCE (shared across both tiles)
#pragma unroll
    for (int j = 0; j < 4; j++) {
        const int idx = t + j * 256;
        const int kw = idx >> 4, cq = idx & 15;
        *reinterpret_cast<float4*>(&sB[kw][cq * 4]) =
            *reinterpret_cast<const float4*>(fcW + kw * 64 + cq * 4);
        *reinterpret_cast<float4*>(&sB[kw][64 + cq * 4]) =
            *reinterpret_cast<const float4*>(fcU + kw * 64 + cq * 4);
    }
    {
        const int kk = t >> 4, cq = t & 15;
        *reinterpret_cast<float4*>(&sWp[kk][cq * 4]) =
            *reinterpret_cast<const float4*>(Wpot + kk * 64 + cq * 4);
    }

    const int c4 = (t & 15) * 4;
    const int r4 = (t >> 4) * 4;
    const float4 as4 = *reinterpret_cast<const float4*>(a + c4);
    const float4 ad4 = *reinterpret_cast<const float4*>(a + 64 + c4);
    const float4 bp4 = *reinterpret_cast<const float4*>(bpot + c4);
    const float4 g4  = *reinterpret_cast<const float4*>(gate + c4);

    for (int rep = 0; rep < 2; rep++) {
        const int m0    = (blockIdx.x + rep * TB2) * BM;
        const int valid = min(BM, NN - m0);

        // stage h tile (transposed) + pot tile
        {
            const int m = t >> 2, q = t & 3;
#pragma unroll
            for (int i = 0; i < 4; i++) {
                const int kg = i * 4 + q;
                float4 v4 = make_float4(0.f, 0.f, 0.f, 0.f);
                if (m < valid)
                    v4 = *reinterpret_cast<const float4*>(hin + (size_t)(m0 + m) * 64 + kg * 4);
                sAt[kg * 4 + 0][m] = v4.x;
                sAt[kg * 4 + 1][m] = v4.y;
                sAt[kg * 4 + 2][m] = v4.z;
                sAt[kg * 4 + 3][m] = v4.w;
            }
            float4 p4 = make_float4(0.f, 0.f, 0.f, 0.f);
            if (m < valid)
                p4 = *reinterpret_cast<const float4*>(pot + (size_t)(m0 + m) * 16 + q * 4);
            *reinterpret_cast<float4*>(&sPot[m][q * 4]) = p4;
        }
        __syncthreads();

        float4 az[4], au[4];
#pragma unroll
        for (int i = 0; i < 4; i++) {
            az[i] = make_float4(0.f, 0.f, 0.f, 0.f);
            au[i] = make_float4(0.f, 0.f, 0.f, 0.f);
        }

#pragma unroll 4
        for (int k = 0; k < 64; k++) {
            const float4 a4 = *reinterpret_cast<const float4*>(&sAt[k][r4]);
            const float4 bw = *reinterpret_cast<const float4*>(&sB[k][c4]);
            const float4 bu = *reinterpret_cast<const float4*>(&sB[k][64 + c4]);
            FMA4(az[0], a4.x, bw); FMA4(au[0], a4.x, bu);
            FMA4(az[1], a4.y, bw); FMA4(au[1], a4.y, bu);
            FMA4(az[2], a4.z, bw); FMA4(au[2], a4.z, bu);
            FMA4(az[3], a4.w, bw); FMA4(au[3], a4.w, bu);
        }

        {
            float ps[4], pd[4];
#pragma unroll
            for (int i = 0; i < 4; i++) { ps[i] = dot4(az[i], as4); pd[i] = dot4(az[i], ad4); }
#pragma unroll
            for (int off = 1; off < 16; off <<= 1) {
#pragma unroll
                for (int i = 0; i < 4; i++) {
                    ps[i] += __shfl_xor(ps[i], off);
                    pd[i] += __shfl_xor(pd[i], off);
                }
            }
            if ((t & 15) == 0) {
#pragma unroll
                for (int i = 0; i < 4; i++) {
                    if (r4 + i < valid) {
                        zs[m0 + r4 + i] = ps[i];
                        zd[m0 + r4 + i] = pd[i];
                    }
                }
            }
        }

        {
            float4 vv[4] = {bp4, bp4, bp4, bp4};
#pragma unroll
            for (int kk = 0; kk < 16; kk++) {
                const float4 wp = *reinterpret_cast<const float4*>(&sWp[kk][c4]);
#pragma unroll
                for (int i = 0; i < 4; i++) {
                    const float pv = sPot[r4 + i][kk];
                    FMA4(vv[i], pv, wp);
                }
            }
#pragma unroll
            for (int i = 0; i < 4; i++) {
                if (r4 + i < valid) {
                    const int n = m0 + r4 + i;
                    uint2 zp;
                    zp.x = pk_bf16(az[i].x, az[i].y);
                    zp.y = pk_bf16(az[i].z, az[i].w);
                    *reinterpret_cast<uint2*>(zb + (size_t)n * 32 + c4 / 2) = zp;
                    float bx = g4.x * tanhf(vv[i].x) * au[i].x;
                    float by = g4.y * tanhf(vv[i].y) * au[i].y;
                    float bz = g4.z * tanhf(vv[i].z) * au[i].z;
                    float bw = g4.w * tanhf(vv[i].w) * au[i].w;
                    uint2 bp;
                    bp.x = pk_bf16(bx, by);
                    bp.y = pk_bf16(bz, bw);
                    *reinterpret_cast<uint2*>(bb + (size_t)n * 32 + c4 / 2) = bp;
                }
            }
        }
        __syncthreads();   // all reads of sAt/sPot done before next rep restages
    }
}

// ---------------- fused softmax + aggregate: TWO nodes per wave, no max-subtract ----
// ep/bb read non-temporally (streamed once) so L2 stays reserved for zb gathers.

__global__ __launch_bounds__(256) void node_sm_agg(
    const int* __restrict__ rowptr, const i2* __restrict__ ep,
    const float* __restrict__ zs, const float* __restrict__ zd,
    const unsigned* __restrict__ zb, const unsigned* __restrict__ bb,
    float* __restrict__ out)
{
    const int lane = threadIdx.x & 63;
    const int half = lane >> 5;          // 0 or 1
    const int sl   = lane & 31;          // sub-lane within half
    const int hb   = half << 5;          // half base lane
    const int n    = blockIdx.x * 8 + ((threadIdx.x >> 6) << 1) + half;
    if (n >= NN) return;

    const int s0  = rowptr[n], s1 = rowptr[n + 1];
    const int deg = s1 - s0;
    const float zdn = zd[n];

    float2 acc = make_float2(0.f, 0.f);
    float ds;

    if (deg <= 32) {
        const int j = s0 + sl;
        int   sv = 0;
        float ex = 0.f;
        if (j < s1) {
            const i2 pr = __builtin_nontemporal_load(ep + j);
            sv = pr[0];
            float v = __int_as_float(pr[1]) + zs[sv] + zdn;
            v = (v >= 0.f) ? v : 0.01f * v;
            ex = __expf(v);
        }
        ds = ex;
#pragma unroll
        for (int off = 16; off; off >>= 1) ds += __shfl_xor(ds, off);

        // uniform loop bound across the wave; ex=0 guards extra iterations
        int mdeg = deg;
        mdeg = max(mdeg, __shfl_xor(mdeg, 32));

        int t = 0;
        for (; t + 8 <= mdeg; t += 8) {
            int ss[8]; float ee[8]; unsigned uu[8];
#pragma unroll
            for (int u = 0; u < 8; u++) {
                ss[u] = __shfl(sv, hb + t + u);
                ee[u] = __shfl(ex, hb + t + u);
            }
#pragma unroll
            for (int u = 0; u < 8; u++) uu[u] = zb[(size_t)ss[u] * 32 + sl];
#pragma unroll
            for (int u = 0; u < 8; u++) {
                const float zl = __uint_as_float(uu[u] << 16);
                const float zh = __uint_as_float(uu[u] & 0xFFFF0000u);
                acc.x = fmaf(ee[u], zl, acc.x);
                acc.y = fmaf(ee[u], zh, acc.y);
            }
        }
        for (; t < mdeg; t++) {
            const int   s = __shfl(sv, hb + t);
            const float e = __shfl(ex, hb + t);
            const unsigned u = zb[(size_t)s * 32 + sl];
            acc.x = fmaf(e, __uint_as_float(u << 16), acc.x);
            acc.y = fmaf(e, __uint_as_float(u & 0xFFFF0000u), acc.y);
        }
    } else {
        // generic fallback (deg > 32): single pass, no max needed.
        ds = 0.f;
        for (int c0 = s0; c0 < s1; c0 += 32) {
            const int j = c0 + sl;
            int   sv = 0;
            float ex = 0.f;
            if (j < s1) {
                const i2 pr = __builtin_nontemporal_load(ep + j);
                sv = pr[0];
                float v = __int_as_float(pr[1]) + zs[sv] + zdn;
                v = (v >= 0.f) ? v : 0.01f * v;
                ex = __expf(v);
            }
            ds += ex;
            const int cnt = min(32, s1 - c0);
            for (int t = 0; t < cnt; t++) {
                const int   s = __shfl(sv, hb + t);
                const float e = __shfl(ex, hb + t);
                const unsigned u = zb[(size_t)s * 32 + sl];
                acc.x = fmaf(e, __uint_as_float(u << 16), acc.x);
                acc.y = fmaf(e, __uint_as_float(u & 0xFFFF0000u), acc.y);
            }
        }
#pragma unroll
        for (int off = 16; off; off >>= 1) ds += __shfl_xor(ds, off);
    }

    const float r = 1.f / ((ds == 0.f) ? 1.f : ds);
    const unsigned bu = __builtin_nontemporal_load(bb + (size_t)n * 32 + sl);
    const size_t o = (size_t)n * 64 + sl * 2;
    float2 res;
    res.x = acc.x * r + __uint_as_float(bu << 16);
    res.y = acc.y * r + __uint_as_float(bu & 0xFFFF0000u);
    *reinterpret_cast<float2*>(out + o) = res;
}

// ---------------- launch ----------------

extern "C" void kernel_launch(void* const* d_in, const int* in_sizes, int n_in,
                              void* d_out, int out_size, void* d_ws, size_t ws_size,
                              hipStream_t stream)
{
    const float* attr  = (const float*)d_in[0];
    const float* pot0  = (const float*)d_in[1];
    const float* pot1  = (const float*)d_in[2];
    const float* et0   = (const float*)d_in[3];
    const float* et1   = (const float*)d_in[4];
    const float* Wpot  = (const float*)d_in[5];
    const float* bpot  = (const float*)d_in[6];
    const float* fcW0  = (const float*)d_in[7];
    const float* fcU0  = (const float*)d_in[8];
    const float* a0    = (const float*)d_in[9];
    const float* gate0 = (const float*)d_in[10];
    const float* fcW1  = (const float*)d_in[11];
    const float* fcU1  = (const float*)d_in[12];
    const float* a1    = (const float*)d_in[13];
    const float* gate1 = (const float*)d_in[14];
    const int*   src   = (const int*)d_in[15];
    const int*   dst   = (const int*)d_in[16];

    float* out = (float*)d_out;

    // workspace layout: 8B-aligned i2 arrays first
    i2*       epA    = (i2*)d_ws;                // EE
    i2*       epB    = epA + EE;                 // EE
    unsigned* zb     = (unsigned*)(epB + EE);    // NN*32 (bf16-packed z)
    unsigned* bb     = zb + NN * 32;             // NN*32 (bf16-packed base)
    float*    zs     = (float*)(bb + NN * 32);   // NN
    float*    zd     = zs + NN;                  // NN
    float*    sc0    = zd + NN;                  // EE
    float*    sc1    = sc0 + EE;                 // EE
    int*      rowptr = (int*)(sc1 + EE);         // NN+1
    int*      deg    = rowptr + NN + 1;          // NN
    int*      rank   = deg + NN;                 // EE

    const int eblk  = (EE + 255) / 256;
    const int nblk2 = (NN + 7) / 8;

    // deg must be zero before hist
    hipMemsetAsync(deg, 0, NN * sizeof(int), stream);

    // edge dots (first) || hist (+rank) — zero LDS, high occupancy
    hist_dot<<<DB + HB, 256, 0, stream>>>(dst, deg, rank, et0, et1, a0, a1, sc0, sc1);

    // transform L0 (2 tiles/block) + fused scan block
    node_transform<<<TB2 + 1, 256, 0, stream>>>(attr, pot0, Wpot, bpot, fcW0, fcU0,
                                                a0, gate0, zb, zs, zd, bb,
                                                deg, rowptr, 1);

    // atomic-free scatter with embedded scores (i2 pairs, nt stores)
    k_scatter<<<eblk, 256, 0, stream>>>(src, dst, rowptr, rank, sc0, sc1, epA, epB);

    // layer 0 aggregate
    node_sm_agg<<<nblk2, 256, 0, stream>>>(rowptr, epA, zs, zd, zb, bb, out);

    // layer 1
    node_transform<<<TB2, 256, 0, stream>>>(out, pot1, Wpot, bpot, fcW1, fcU1,
                                            a1, gate1, zb, zs, zd, bb,
                                            deg, rowptr, 0);
    node_sm_agg<<<nblk2, 256, 0, stream>>>(rowptr, epB, zs, zd, zb, bb, out);
}

// Round 20
// 297.917 us; speedup vs baseline: 1.0990x; 1.0990x over previous
//
#include <hip/hip_runtime.h>
#include <math.h>

#define NN 50000
#define EE 800000
#define BM 64
#define HB 3125                  // hist blocks (EE/256 exactly)
#define DB 5000                  // dot blocks
#define DS3 (DB * 256)           // 1,280,000; (EE*16) % (DS3*2) == 0 -> 5 iters
#define TB2 391                  // transform blocks (each does 2 tiles; 782 tiles total)

typedef float f4 __attribute__((ext_vector_type(4)));

// ---------------- helpers ----------------

#define FMA4(acc, s, v) do { \
    (acc).x = fmaf((s), (v).x, (acc).x); \
    (acc).y = fmaf((s), (v).y, (acc).y); \
    (acc).z = fmaf((s), (v).z, (acc).z); \
    (acc).w = fmaf((s), (v).w, (acc).w); } while (0)

__device__ __forceinline__ float dot4(float4 u, float4 v) {
    return fmaf(u.x, v.x, fmaf(u.y, v.y, fmaf(u.z, v.z, u.w * v.w)));
}

// pack two finite floats to bf16 (RNE) in one uint: lo = feature even, hi = odd
__device__ __forceinline__ unsigned pk_bf16(float lo, float hi) {
    union { float f; unsigned u; } a, b;
    a.f = lo; b.f = hi;
    unsigned alo = (a.u + 0x7FFFu + ((a.u >> 16) & 1u)) >> 16;
    unsigned bhi = (b.u + 0x7FFFu + ((b.u >> 16) & 1u)) >> 16;
    return (bhi << 16) | alo;
}

// ---------------- fused edge dots + histogram (dot blocks FIRST) ----------------

__global__ __launch_bounds__(256) void hist_dot(
    const int* __restrict__ dst, int* __restrict__ deg, int* __restrict__ rank,
    const float* __restrict__ et0, const float* __restrict__ et1,
    const float* __restrict__ a0, const float* __restrict__ a1,
    float* __restrict__ sc0, float* __restrict__ sc1)
{
    const int bid = blockIdx.x;

    if (bid < DB) {
        // streaming edge dots (NT loads, lane-contiguous, 2-deep unroll)
        const int tid  = bid * 256 + threadIdx.x;
        const int lane = threadIdx.x & 63;
        const int p    = tid & 15;
        const float4 A0 = *reinterpret_cast<const float4*>(a0 + 128 + p * 4);
        const float4 A1 = *reinterpret_cast<const float4*>(a1 + 128 + p * 4);
        const f4* __restrict__ e0 = reinterpret_cast<const f4*>(et0);
        const f4* __restrict__ e1 = reinterpret_cast<const f4*>(et1);

        for (int i = tid; i < EE * 16; i += DS3 * 2) {
            f4 v0[2], v1[2];
#pragma unroll
            for (int u = 0; u < 2; u++) v0[u] = __builtin_nontemporal_load(e0 + i + u * DS3);
#pragma unroll
            for (int u = 0; u < 2; u++) v1[u] = __builtin_nontemporal_load(e1 + i + u * DS3);
            float r0[2], r1[2];
#pragma unroll
            for (int u = 0; u < 2; u++) {
                r0[u] = fmaf(v0[u][0], A0.x, fmaf(v0[u][1], A0.y, fmaf(v0[u][2], A0.z, v0[u][3] * A0.w)));
                r1[u] = fmaf(v1[u][0], A1.x, fmaf(v1[u][1], A1.y, fmaf(v1[u][2], A1.z, v1[u][3] * A1.w)));
            }
#pragma unroll
            for (int u = 0; u < 2; u++) {
#pragma unroll
                for (int off = 8; off; off >>= 1) {
                    r0[u] += __shfl_xor(r0[u], off);
                    r1[u] += __shfl_xor(r1[u], off);
                }
            }
            if ((lane & 15) == 0) {
#pragma unroll
                for (int u = 0; u < 2; u++) {
                    const int e = (i + u * DS3) >> 4;
                    sc0[e] = r0[u];
                    sc1[e] = r1[u];
                }
            }
        }
    } else {
        // histogram + per-edge rank (atomicAdd return = rank within segment)
        const int e = (bid - DB) * 256 + threadIdx.x;   // HB*256 == EE exactly
        rank[e] = atomicAdd(&deg[dst[e]], 1);
    }
}

// ---------------- atomic-free scatter: epX[p] = {src, score bits} ----------------

__global__ __launch_bounds__(256) void k_scatter(
    const int* __restrict__ src, const int* __restrict__ dst,
    const int* __restrict__ rowptr, const int* __restrict__ rank,
    const float* __restrict__ sc0, const float* __restrict__ sc1,
    int2* __restrict__ epA, int2* __restrict__ epB)
{
    int e = blockIdx.x * 256 + threadIdx.x;
    if (e < EE) {
        const int p = rowptr[dst[e]] + rank[e];
        const int s = src[e];
        epA[p] = make_int2(s, __float_as_int(sc0[e]));
        epB[p] = make_int2(s, __float_as_int(sc1[e]));
    }
}

// ---------------- node transform (LDS-tiled GEMM, 2 tiles/block) + fused scan ----------------

__global__ __launch_bounds__(256) void node_transform(
    const float* __restrict__ hin, const float* __restrict__ pot,
    const float* __restrict__ Wpot, const float* __restrict__ bpot,
    const float* __restrict__ fcW, const float* __restrict__ fcU,
    const float* __restrict__ a, const float* __restrict__ gate,
    unsigned* __restrict__ zb, float* __restrict__ zs, float* __restrict__ zd,
    unsigned* __restrict__ bb,
    const int* __restrict__ deg, int* __restrict__ rowptr, int do_scan)
{
    __shared__ float sAt[64][64];
    __shared__ float sB[64][128];
    __shared__ float sPot[64][16];
    __shared__ float sWp[16][64];

    const int t = threadIdx.x;

    if (do_scan && blockIdx.x == TB2) {
        // 256-thread exclusive scan of deg -> rowptr (rides in this dispatch)
        int* part = reinterpret_cast<int*>(&sAt[0][0]);
        const int CH = (NN + 255) / 256;
        const int b  = t * CH;
        const int e  = min(b + CH, NN);
        int sum = 0;
        for (int i = b; i < e; i++) sum += deg[i];
        part[t] = sum;
        __syncthreads();
        for (int off = 1; off < 256; off <<= 1) {
            int v = (t >= off) ? part[t - off] : 0;
            __syncthreads();
            part[t] += v;
            __syncthreads();
        }
        int run = (t == 0) ? 0 : part[t - 1];
        for (int i = b; i < e; i++) {
            rowptr[i] = run;
            run += deg[i];
        }
        if (t == 0) rowptr[NN] = EE;
        return;
    }

    // stage weights ONCE (shared across both tiles)
#pragma unroll
    for (int j = 0; j < 4; j++) {
        const int idx = t + j * 256;
        const int kw = idx >> 4, cq = idx & 15;
        *reinterpret_cast<float4*>(&sB[kw][cq * 4]) =
            *reinterpret_cast<const float4*>(fcW + kw * 64 + cq * 4);
        *reinterpret_cast<float4*>(&sB[kw][64 + cq * 4]) =
            *reinterpret_cast<const float4*>(fcU + kw * 64 + cq * 4);
    }
    {
        const int kk = t >> 4, cq = t & 15;
        *reinterpret_cast<float4*>(&sWp[kk][cq * 4]) =
            *reinterpret_cast<const float4*>(Wpot + kk * 64 + cq * 4);
    }

    const int c4 = (t & 15) * 4;
    const int r4 = (t >> 4) * 4;
    const float4 as4 = *reinterpret_cast<const float4*>(a + c4);
    const float4 ad4 = *reinterpret_cast<const float4*>(a + 64 + c4);
    const float4 bp4 = *reinterpret_cast<const float4*>(bpot + c4);
    const float4 g4  = *reinterpret_cast<const float4*>(gate + c4);

    for (int rep = 0; rep < 2; rep++) {
        const int m0    = (blockIdx.x + rep * TB2) * BM;
        const int valid = min(BM, NN - m0);

        // stage h tile (transposed) + pot tile
        {
            const int m = t >> 2, q = t & 3;
#pragma unroll
            for (int i = 0; i < 4; i++) {
                const int kg = i * 4 + q;
                float4 v4 = make_float4(0.f, 0.f, 0.f, 0.f);
                if (m < valid)
                    v4 = *reinterpret_cast<const float4*>(hin + (size_t)(m0 + m) * 64 + kg * 4);
                sAt[kg * 4 + 0][m] = v4.x;
                sAt[kg * 4 + 1][m] = v4.y;
                sAt[kg * 4 + 2][m] = v4.z;
                sAt[kg * 4 + 3][m] = v4.w;
            }
            float4 p4 = make_float4(0.f, 0.f, 0.f, 0.f);
            if (m < valid)
                p4 = *reinterpret_cast<const float4*>(pot + (size_t)(m0 + m) * 16 + q * 4);
            *reinterpret_cast<float4*>(&sPot[m][q * 4]) = p4;
        }
        __syncthreads();

        float4 az[4], au[4];
#pragma unroll
        for (int i = 0; i < 4; i++) {
            az[i] = make_float4(0.f, 0.f, 0.f, 0.f);
            au[i] = make_float4(0.f, 0.f, 0.f, 0.f);
        }

#pragma unroll 4
        for (int k = 0; k < 64; k++) {
            const float4 a4 = *reinterpret_cast<const float4*>(&sAt[k][r4]);
            const float4 bw = *reinterpret_cast<const float4*>(&sB[k][c4]);
            const float4 bu = *reinterpret_cast<const float4*>(&sB[k][64 + c4]);
            FMA4(az[0], a4.x, bw); FMA4(au[0], a4.x, bu);
            FMA4(az[1], a4.y, bw); FMA4(au[1], a4.y, bu);
            FMA4(az[2], a4.z, bw); FMA4(au[2], a4.z, bu);
            FMA4(az[3], a4.w, bw); FMA4(au[3], a4.w, bu);
        }

        {
            float ps[4], pd[4];
#pragma unroll
            for (int i = 0; i < 4; i++) { ps[i] = dot4(az[i], as4); pd[i] = dot4(az[i], ad4); }
#pragma unroll
            for (int off = 1; off < 16; off <<= 1) {
#pragma unroll
                for (int i = 0; i < 4; i++) {
                    ps[i] += __shfl_xor(ps[i], off);
                    pd[i] += __shfl_xor(pd[i], off);
                }
            }
            if ((t & 15) == 0) {
#pragma unroll
                for (int i = 0; i < 4; i++) {
                    if (r4 + i < valid) {
                        zs[m0 + r4 + i] = ps[i];
                        zd[m0 + r4 + i] = pd[i];
                    }
                }
            }
        }

        {
            float4 vv[4] = {bp4, bp4, bp4, bp4};
#pragma unroll
            for (int kk = 0; kk < 16; kk++) {
                const float4 wp = *reinterpret_cast<const float4*>(&sWp[kk][c4]);
#pragma unroll
                for (int i = 0; i < 4; i++) {
                    const float pv = sPot[r4 + i][kk];
                    FMA4(vv[i], pv, wp);
                }
            }
#pragma unroll
            for (int i = 0; i < 4; i++) {
                if (r4 + i < valid) {
                    const int n = m0 + r4 + i;
                    uint2 zp;
                    zp.x = pk_bf16(az[i].x, az[i].y);
                    zp.y = pk_bf16(az[i].z, az[i].w);
                    *reinterpret_cast<uint2*>(zb + (size_t)n * 32 + c4 / 2) = zp;
                    float bx = g4.x * tanhf(vv[i].x) * au[i].x;
                    float by = g4.y * tanhf(vv[i].y) * au[i].y;
                    float bz = g4.z * tanhf(vv[i].z) * au[i].z;
                    float bw = g4.w * tanhf(vv[i].w) * au[i].w;
                    uint2 bp;
                    bp.x = pk_bf16(bx, by);
                    bp.y = pk_bf16(bz, bw);
                    *reinterpret_cast<uint2*>(bb + (size_t)n * 32 + c4 / 2) = bp;
                }
            }
        }
        __syncthreads();   // all reads of sAt/sPot done before next rep restages
    }
}

// ---------------- fused softmax + aggregate: TWO nodes per wave, no max-subtract ----

__global__ __launch_bounds__(256) void node_sm_agg(
    const int* __restrict__ rowptr, const int2* __restrict__ ep,
    const float* __restrict__ zs, const float* __restrict__ zd,
    const unsigned* __restrict__ zb, const unsigned* __restrict__ bb,
    float* __restrict__ out)
{
    const int lane = threadIdx.x & 63;
    const int half = lane >> 5;          // 0 or 1
    const int sl   = lane & 31;          // sub-lane within half
    const int hb   = half << 5;          // half base lane
    const int n    = blockIdx.x * 8 + ((threadIdx.x >> 6) << 1) + half;
    if (n >= NN) return;

    const int s0  = rowptr[n], s1 = rowptr[n + 1];
    const int deg = s1 - s0;
    const float zdn = zd[n];

    float2 acc = make_float2(0.f, 0.f);
    float ds;

    if (deg <= 32) {
        const int j = s0 + sl;
        int   sv = 0;
        float ex = 0.f;
        if (j < s1) {
            const int2 pr = ep[j];
            sv = pr.x;
            float v = __int_as_float(pr.y) + zs[sv] + zdn;
            v = (v >= 0.f) ? v : 0.01f * v;
            ex = __expf(v);
        }
        ds = ex;
#pragma unroll
        for (int off = 16; off; off >>= 1) ds += __shfl_xor(ds, off);

        // uniform loop bound across the wave; ex=0 guards extra iterations
        int mdeg = deg;
        mdeg = max(mdeg, __shfl_xor(mdeg, 32));

        int t = 0;
        for (; t + 8 <= mdeg; t += 8) {
            int ss[8]; float ee[8]; unsigned uu[8];
#pragma unroll
            for (int u = 0; u < 8; u++) {
                ss[u] = __shfl(sv, hb + t + u);
                ee[u] = __shfl(ex, hb + t + u);
            }
#pragma unroll
            for (int u = 0; u < 8; u++) uu[u] = zb[(size_t)ss[u] * 32 + sl];
#pragma unroll
            for (int u = 0; u < 8; u++) {
                const float zl = __uint_as_float(uu[u] << 16);
                const float zh = __uint_as_float(uu[u] & 0xFFFF0000u);
                acc.x = fmaf(ee[u], zl, acc.x);
                acc.y = fmaf(ee[u], zh, acc.y);
            }
        }
        for (; t < mdeg; t++) {
            const int   s = __shfl(sv, hb + t);
            const float e = __shfl(ex, hb + t);
            const unsigned u = zb[(size_t)s * 32 + sl];
            acc.x = fmaf(e, __uint_as_float(u << 16), acc.x);
            acc.y = fmaf(e, __uint_as_float(u & 0xFFFF0000u), acc.y);
        }
    } else {
        // generic fallback (deg > 32): single pass, no max needed.
        ds = 0.f;
        for (int c0 = s0; c0 < s1; c0 += 32) {
            const int j = c0 + sl;
            int   sv = 0;
            float ex = 0.f;
            if (j < s1) {
                const int2 pr = ep[j];
                sv = pr.x;
                float v = __int_as_float(pr.y) + zs[sv] + zdn;
                v = (v >= 0.f) ? v : 0.01f * v;
                ex = __expf(v);
            }
            ds += ex;
            const int cnt = min(32, s1 - c0);
            for (int t = 0; t < cnt; t++) {
                const int   s = __shfl(sv, hb + t);
                const float e = __shfl(ex, hb + t);
                const unsigned u = zb[(size_t)s * 32 + sl];
                acc.x = fmaf(e, __uint_as_float(u << 16), acc.x);
                acc.y = fmaf(e, __uint_as_float(u & 0xFFFF0000u), acc.y);
            }
        }
#pragma unroll
        for (int off = 16; off; off >>= 1) ds += __shfl_xor(ds, off);
    }

    const float r = 1.f / ((ds == 0.f) ? 1.f : ds);
    const unsigned bu = bb[(size_t)n * 32 + sl];
    const size_t o = (size_t)n * 64 + sl * 2;
    float2 res;
    res.x = acc.x * r + __uint_as_float(bu << 16);
    res.y = acc.y * r + __uint_as_float(bu & 0xFFFF0000u);
    *reinterpret_cast<float2*>(out + o) = res;
}

// ---------------- launch ----------------

extern "C" void kernel_launch(void* const* d_in, const int* in_sizes, int n_in,
                              void* d_out, int out_size, void* d_ws, size_t ws_size,
                              hipStream_t stream)
{
    const float* attr  = (const float*)d_in[0];
    const float* pot0  = (const float*)d_in[1];
    const float* pot1  = (const float*)d_in[2];
    const float* et0   = (const float*)d_in[3];
    const float* et1   = (const float*)d_in[4];
    const float* Wpot  = (const float*)d_in[5];
    const float* bpot  = (const float*)d_in[6];
    const float* fcW0  = (const float*)d_in[7];
    const float* fcU0  = (const float*)d_in[8];
    const float* a0    = (const float*)d_in[9];
    const float* gate0 = (const float*)d_in[10];
    const float* fcW1  = (const float*)d_in[11];
    const float* fcU1  = (const float*)d_in[12];
    const float* a1    = (const float*)d_in[13];
    const float* gate1 = (const float*)d_in[14];
    const int*   src   = (const int*)d_in[15];
    const int*   dst   = (const int*)d_in[16];

    float* out = (float*)d_out;

    // workspace layout: 8B-aligned int2 arrays first
    int2*     epA    = (int2*)d_ws;              // EE
    int2*     epB    = epA + EE;                 // EE
    unsigned* zb     = (unsigned*)(epB + EE);    // NN*32 (bf16-packed z)
    unsigned* bb     = zb + NN * 32;             // NN*32 (bf16-packed base)
    float*    zs     = (float*)(bb + NN * 32);   // NN
    float*    zd     = zs + NN;                  // NN
    float*    sc0    = zd + NN;                  // EE
    float*    sc1    = sc0 + EE;                 // EE
    int*      rowptr = (int*)(sc1 + EE);         // NN+1
    int*      deg    = rowptr + NN + 1;          // NN
    int*      rank   = deg + NN;                 // EE

    const int eblk  = (EE + 255) / 256;
    const int nblk2 = (NN + 7) / 8;

    // deg must be zero before hist
    hipMemsetAsync(deg, 0, NN * sizeof(int), stream);

    // edge dots (first) || hist (+rank) — zero LDS, high occupancy
    hist_dot<<<DB + HB, 256, 0, stream>>>(dst, deg, rank, et0, et1, a0, a1, sc0, sc1);

    // transform L0 (2 tiles/block) + fused scan block
    node_transform<<<TB2 + 1, 256, 0, stream>>>(attr, pot0, Wpot, bpot, fcW0, fcU0,
                                                a0, gate0, zb, zs, zd, bb,
                                                deg, rowptr, 1);

    // atomic-free scatter with embedded scores (int2 pairs)
    k_scatter<<<eblk, 256, 0, stream>>>(src, dst, rowptr, rank, sc0, sc1, epA, epB);

    // layer 0 aggregate
    node_sm_agg<<<nblk2, 256, 0, stream>>>(rowptr, epA, zs, zd, zb, bb, out);

    // layer 1
    node_transform<<<TB2, 256, 0, stream>>>(out, pot1, Wpot, bpot, fcW1, fcU1,
                                            a1, gate1, zb, zs, zd, bb,
                                            deg, rowptr, 0);
    node_sm_agg<<<nblk2, 256, 0, stream>>>(rowptr, epB, zs, zd, zb, bb, out);
}